// Round 1
// baseline (43690.466 us; speedup 1.0000x reference)
//
#include <hip/hip_runtime.h>
#include <hip/hip_bf16.h>
#include <cstdint>
#include <cstddef>

// Problem constants (from reference: T=16384, H=512)
constexpr int HD   = 512;    // hidden size
constexpr int G4H  = 2048;   // 4*H
constexpr int NWG  = 16;     // workgroups in recurrence kernel
// Each WG owns 32 cells -> 4 gates * 32 = 128 rows of w_hh.

// ---------- xg type helpers (fp32 or bf16 scratch, chosen by ws_size) ----------
__device__ inline float xg_load1(const float* p) { return *p; }
__device__ inline float xg_load1(const __hip_bfloat16* p) { return __bfloat162float(*p); }

__device__ inline void xg_store4(float* p, float a, float b, float c, float d) {
  *reinterpret_cast<float4*>(p) = make_float4(a, b, c, d);
}
__device__ inline void xg_store4(__hip_bfloat16* p, float a, float b, float c, float d) {
  p[0] = __float2bfloat16(a); p[1] = __float2bfloat16(b);
  p[2] = __float2bfloat16(c); p[3] = __float2bfloat16(d);
}

// ============================================================================
// Phase A: xg[T, 2048] = input[T,512] @ w_ih[2048,512]^T + b_ih
// fp32 vector-ALU tiled GEMM (no fp32 MFMA on CDNA4). 64x64 tile, 256 thr,
// 4x4 microtile, K-tiles of 16.
// ============================================================================
template <typename TXG>
__global__ __launch_bounds__(256) void xg_gemm(const float* __restrict__ A,
                                               const float* __restrict__ W,
                                               const float* __restrict__ bias,
                                               TXG* __restrict__ xg) {
  __shared__ float As[16][68];  // [k][row], pad to 68 (272B rows, 16B aligned)
  __shared__ float Ws[16][68];
  const int u = threadIdx.x;
  const int n0 = blockIdx.x * 64;
  const int m0 = blockIdx.y * 64;
  const int lrow = u >> 2;         // 0..63
  const int kq = (u & 3) << 2;     // 0,4,8,12
  const int ty = u >> 4;           // 0..15
  const int tx = u & 15;           // 0..15

  float acc[4][4] = {};
  for (int k0 = 0; k0 < HD; k0 += 16) {
    const float4 av = *reinterpret_cast<const float4*>(A + (size_t)(m0 + lrow) * HD + k0 + kq);
    const float4 wv = *reinterpret_cast<const float4*>(W + (size_t)(n0 + lrow) * HD + k0 + kq);
    __syncthreads();  // protect previous iteration's LDS reads
    As[kq + 0][lrow] = av.x; As[kq + 1][lrow] = av.y;
    As[kq + 2][lrow] = av.z; As[kq + 3][lrow] = av.w;
    Ws[kq + 0][lrow] = wv.x; Ws[kq + 1][lrow] = wv.y;
    Ws[kq + 2][lrow] = wv.z; Ws[kq + 3][lrow] = wv.w;
    __syncthreads();
#pragma unroll
    for (int kk = 0; kk < 16; ++kk) {
      const float4 a4 = *reinterpret_cast<const float4*>(&As[kk][ty << 2]);
      const float4 b4 = *reinterpret_cast<const float4*>(&Ws[kk][tx << 2]);
      acc[0][0] = fmaf(a4.x, b4.x, acc[0][0]);
      acc[0][1] = fmaf(a4.x, b4.y, acc[0][1]);
      acc[0][2] = fmaf(a4.x, b4.z, acc[0][2]);
      acc[0][3] = fmaf(a4.x, b4.w, acc[0][3]);
      acc[1][0] = fmaf(a4.y, b4.x, acc[1][0]);
      acc[1][1] = fmaf(a4.y, b4.y, acc[1][1]);
      acc[1][2] = fmaf(a4.y, b4.z, acc[1][2]);
      acc[1][3] = fmaf(a4.y, b4.w, acc[1][3]);
      acc[2][0] = fmaf(a4.z, b4.x, acc[2][0]);
      acc[2][1] = fmaf(a4.z, b4.y, acc[2][1]);
      acc[2][2] = fmaf(a4.z, b4.z, acc[2][2]);
      acc[2][3] = fmaf(a4.z, b4.w, acc[2][3]);
      acc[3][0] = fmaf(a4.w, b4.x, acc[3][0]);
      acc[3][1] = fmaf(a4.w, b4.y, acc[3][1]);
      acc[3][2] = fmaf(a4.w, b4.z, acc[3][2]);
      acc[3][3] = fmaf(a4.w, b4.w, acc[3][3]);
    }
  }
  const int n = n0 + (tx << 2);
  const float b0 = bias[n + 0], b1 = bias[n + 1], b2 = bias[n + 2], b3 = bias[n + 3];
#pragma unroll
  for (int i = 0; i < 4; ++i) {
    const int m = m0 + (ty << 2) + i;
    xg_store4(xg + (size_t)m * G4H + n,
              acc[i][0] + b0, acc[i][1] + b1, acc[i][2] + b2, acc[i][3] + b3);
  }
}

// ============================================================================
// Phase B: persistent recurrence. 16 WGs x 512 threads.
// WG m owns cells j in [m*32, m*32+32): rows {q*512 + m*32 + j}, q=0..3 (IFGO).
// Weights fp32-resident in VGPRs: thread (wave,lane): p=wave>>1 (col quarter),
// r=(wave&1)*64+lane (local row 0..127), holds w_hh[grow][p*128 .. +128).
// Per step: wave-uniform float4 broadcast reads of h from LDS + 128 FMAs,
// LDS reduction over the 4 col-parts, 32 threads update c/h, then a
// device-scope counter barrier + double-buffered global h exchange
// (agent-scope atomics: per-XCD L2s are not coherent).
// ============================================================================
template <typename TXG>
__global__ __launch_bounds__(512, 2) void lstm_rec(const TXG* __restrict__ xg,
                                                   const float* __restrict__ w_hh,
                                                   float* __restrict__ out,
                                                   float* __restrict__ hbuf,  // [2][512]
                                                   unsigned* __restrict__ ctr,
                                                   int T) {
  const int m = blockIdx.x;          // 0..15
  const int tid = threadIdx.x;       // 0..511
  const int wave = tid >> 6;
  const int lane = tid & 63;
  const int p = wave >> 1;                     // col part 0..3
  const int r = ((wave & 1) << 6) + lane;      // local row 0..127
  const int q = r >> 5;                        // gate (0=i,1=f,2=g,3=o)
  const int j = r & 31;                        // cell within slice
  const int grow = q * HD + m * 32 + j;        // global row in w_hh [0,2048)

  // Load resident weights (exact fp32), 128 per thread.
  float w[128];
  {
    const float* wp = w_hh + (size_t)grow * HD + p * 128;
#pragma unroll
    for (int i = 0; i < 32; ++i) {
      const float4 v = *reinterpret_cast<const float4*>(wp + 4 * i);
      w[4 * i + 0] = v.x; w[4 * i + 1] = v.y; w[4 * i + 2] = v.z; w[4 * i + 3] = v.w;
    }
  }

  __shared__ float h_lds[HD];
  __shared__ float red[4][128];
  __shared__ float act[128];

  float c = 0.0f;       // cell state for tid<32 (cell j=tid)
  h_lds[tid] = 0.0f;    // h0 = 0
  __syncthreads();

  // xg prefetch (for t=0)
  const int xcol = (tid >> 5) * HD + m * 32 + (tid & 31);  // global gate col for tid<128
  float xgv = (tid < 128) ? xg_load1(xg + xcol) : 0.0f;

  for (int t = 0; t < T; ++t) {
    // Prefetch next step's xg early; consumed next iteration (latency hidden
    // behind this step's dot + global barrier).
    float xgv_n = 0.0f;
    if (tid < 128 && t + 1 < T) xgv_n = xg_load1(xg + (size_t)(t + 1) * G4H + xcol);

    // ---- dot: partial over 128 cols, wave-uniform LDS broadcast reads ----
    const float4* hv4 = reinterpret_cast<const float4*>(h_lds + p * 128);
    float a0 = 0.f, a1 = 0.f, a2 = 0.f, a3 = 0.f;
#pragma unroll
    for (int i = 0; i < 32; ++i) {
      const float4 hv = hv4[i];
      a0 = fmaf(w[4 * i + 0], hv.x, a0);
      a1 = fmaf(w[4 * i + 1], hv.y, a1);
      a2 = fmaf(w[4 * i + 2], hv.z, a2);
      a3 = fmaf(w[4 * i + 3], hv.w, a3);
    }
    red[p][r] = (a0 + a1) + (a2 + a3);
    __syncthreads();

    // ---- gate activations (tid<128: one gate value each) ----
    if (tid < 128) {
      const float pre = red[0][tid] + red[1][tid] + red[2][tid] + red[3][tid] + xgv;
      act[tid] = ((tid >> 5) == 2) ? tanhf(pre) : (1.0f / (1.0f + __expf(-pre)));
    }
    __syncthreads();

    // ---- cell update (tid<32: cell m*32+tid) ----
    if (tid < 32) {
      const float i_ = act[tid], f_ = act[32 + tid], g_ = act[64 + tid], o_ = act[96 + tid];
      c = fmaf(f_, c, i_ * g_);
      const float h = o_ * tanhf(c);
      out[(size_t)t * HD + m * 32 + tid] = h;
      // agent-scope store: must reach the device-coherent point (cross-XCD)
      __hip_atomic_store(&hbuf[(t & 1) * HD + m * 32 + tid], h,
                         __ATOMIC_RELAXED, __HIP_MEMORY_SCOPE_AGENT);
    }
    __syncthreads();  // drains vmcnt: slice stores complete before the flag

    // ---- global barrier across the 16 WGs ----
    if (tid == 0) {
      __hip_atomic_fetch_add(ctr, 1u, __ATOMIC_RELEASE, __HIP_MEMORY_SCOPE_AGENT);
      const unsigned target = (unsigned)(t + 1) * NWG;
      while (__hip_atomic_load(ctr, __ATOMIC_RELAXED, __HIP_MEMORY_SCOPE_AGENT) < target) {
        __builtin_amdgcn_s_sleep(1);
      }
    }
    __syncthreads();

    // ---- reload full h (fresh, bypassing stale L1/L2 via agent-scope loads) ----
    h_lds[tid] = __hip_atomic_load(&hbuf[(t & 1) * HD + tid],
                                   __ATOMIC_RELAXED, __HIP_MEMORY_SCOPE_AGENT);
    __syncthreads();

    xgv = xgv_n;
  }
}

// ============================================================================
extern "C" void kernel_launch(void* const* d_in, const int* in_sizes, int n_in,
                              void* d_out, int out_size, void* d_ws, size_t ws_size,
                              hipStream_t stream) {
  const float* input = (const float*)d_in[0];
  const float* w_ih  = (const float*)d_in[1];
  const float* w_hh  = (const float*)d_in[2];
  const float* b_ih  = (const float*)d_in[3];
  float* out = (float*)d_out;
  const int T = in_sizes[0] / HD;  // 16384

  const size_t xgF32  = (size_t)T * G4H * sizeof(float);
  const size_t xgBF16 = (size_t)T * G4H * sizeof(__hip_bfloat16);
  const bool useF32 = (ws_size >= xgF32 + 8192);  // host-side, constant per session
  const size_t xgBytes = useF32 ? xgF32 : xgBF16;

  char* ws = (char*)d_ws;
  float* hbuf = (float*)(ws + ((xgBytes + 255) & ~(size_t)255));
  unsigned* ctr = (unsigned*)((char*)hbuf + 2 * HD * sizeof(float));
  // zero h double-buffer + barrier counter (ws is poisoned 0xAA each call)
  hipMemsetAsync(hbuf, 0, 2 * HD * sizeof(float) + 64, stream);

  const dim3 gA(G4H / 64, T / 64);
  if (useF32) {
    float* xg = (float*)ws;
    xg_gemm<float><<<gA, 256, 0, stream>>>(input, w_ih, b_ih, xg);
    lstm_rec<float><<<NWG, 512, 0, stream>>>(xg, w_hh, out, hbuf, ctr, T);
  } else {
    __hip_bfloat16* xg = (__hip_bfloat16*)ws;
    xg_gemm<__hip_bfloat16><<<gA, 256, 0, stream>>>(input, w_ih, b_ih, xg);
    lstm_rec<__hip_bfloat16><<<NWG, 512, 0, stream>>>(xg, w_hh, out, hbuf, ctr, T);
  }
}

// Round 2
// 30428.464 us; speedup vs baseline: 1.4358x; 1.4358x over previous
//
#include <hip/hip_runtime.h>
#include <hip/hip_bf16.h>
#include <cstdint>
#include <cstddef>

// Problem constants (from reference: T=16384, H=512)
constexpr int HD   = 512;    // hidden size
constexpr int G4H  = 2048;   // 4*H
constexpr int NWG  = 16;     // workgroups in recurrence kernel

// ---------- xg type helpers (fp32 or bf16 scratch, chosen by ws_size) ----------
__device__ inline float xg_load1(const float* p) { return *p; }
__device__ inline float xg_load1(const __hip_bfloat16* p) { return __bfloat162float(*p); }

__device__ inline void xg_store4(float* p, float a, float b, float c, float d) {
  *reinterpret_cast<float4*>(p) = make_float4(a, b, c, d);
}
__device__ inline void xg_store4(__hip_bfloat16* p, float a, float b, float c, float d) {
  p[0] = __float2bfloat16(a); p[1] = __float2bfloat16(b);
  p[2] = __float2bfloat16(c); p[3] = __float2bfloat16(d);
}

// fast activations (v_exp_f32-based; |err| ~1e-6, threshold is 1.8e-2)
__device__ inline float sigmoid_f(float x) { return 1.0f / (1.0f + __expf(-x)); }
__device__ inline float tanh_f(float x)    { return 2.0f / (1.0f + __expf(-2.0f * x)) - 1.0f; }

// ============================================================================
// Phase A: xg[T, 2048] = input[T,512] @ w_ih[2048,512]^T + b_ih
// fp32 vector-ALU tiled GEMM (no fp32 MFMA on CDNA4). 64x64 tile, 256 thr,
// 4x4 microtile, K-tiles of 16.  (<1 ms of the 43.7 ms total — left as-is.)
// ============================================================================
template <typename TXG>
__global__ __launch_bounds__(256) void xg_gemm(const float* __restrict__ A,
                                               const float* __restrict__ W,
                                               const float* __restrict__ bias,
                                               TXG* __restrict__ xg) {
  __shared__ float As[16][68];
  __shared__ float Ws[16][68];
  const int u = threadIdx.x;
  const int n0 = blockIdx.x * 64;
  const int m0 = blockIdx.y * 64;
  const int lrow = u >> 2;
  const int kq = (u & 3) << 2;
  const int ty = u >> 4;
  const int tx = u & 15;

  float acc[4][4] = {};
  for (int k0 = 0; k0 < HD; k0 += 16) {
    const float4 av = *reinterpret_cast<const float4*>(A + (size_t)(m0 + lrow) * HD + k0 + kq);
    const float4 wv = *reinterpret_cast<const float4*>(W + (size_t)(n0 + lrow) * HD + k0 + kq);
    __syncthreads();
    As[kq + 0][lrow] = av.x; As[kq + 1][lrow] = av.y;
    As[kq + 2][lrow] = av.z; As[kq + 3][lrow] = av.w;
    Ws[kq + 0][lrow] = wv.x; Ws[kq + 1][lrow] = wv.y;
    Ws[kq + 2][lrow] = wv.z; Ws[kq + 3][lrow] = wv.w;
    __syncthreads();
#pragma unroll
    for (int kk = 0; kk < 16; ++kk) {
      const float4 a4 = *reinterpret_cast<const float4*>(&As[kk][ty << 2]);
      const float4 b4 = *reinterpret_cast<const float4*>(&Ws[kk][tx << 2]);
      acc[0][0] = fmaf(a4.x, b4.x, acc[0][0]);
      acc[0][1] = fmaf(a4.x, b4.y, acc[0][1]);
      acc[0][2] = fmaf(a4.x, b4.z, acc[0][2]);
      acc[0][3] = fmaf(a4.x, b4.w, acc[0][3]);
      acc[1][0] = fmaf(a4.y, b4.x, acc[1][0]);
      acc[1][1] = fmaf(a4.y, b4.y, acc[1][1]);
      acc[1][2] = fmaf(a4.y, b4.z, acc[1][2]);
      acc[1][3] = fmaf(a4.y, b4.w, acc[1][3]);
      acc[2][0] = fmaf(a4.z, b4.x, acc[2][0]);
      acc[2][1] = fmaf(a4.z, b4.y, acc[2][1]);
      acc[2][2] = fmaf(a4.z, b4.z, acc[2][2]);
      acc[2][3] = fmaf(a4.z, b4.w, acc[2][3]);
      acc[3][0] = fmaf(a4.w, b4.x, acc[3][0]);
      acc[3][1] = fmaf(a4.w, b4.y, acc[3][1]);
      acc[3][2] = fmaf(a4.w, b4.z, acc[3][2]);
      acc[3][3] = fmaf(a4.w, b4.w, acc[3][3]);
    }
  }
  const int n = n0 + (tx << 2);
  const float b0 = bias[n + 0], b1 = bias[n + 1], b2 = bias[n + 2], b3 = bias[n + 3];
#pragma unroll
  for (int i = 0; i < 4; ++i) {
    const int m = m0 + (ty << 2) + i;
    xg_store4(xg + (size_t)m * G4H + n,
              acc[i][0] + b0, acc[i][1] + b1, acc[i][2] + b2, acc[i][3] + b3);
  }
}

// ============================================================================
// Phase B: persistent recurrence. 16 WGs x 512 threads.
// h exchange: each h element is a 64-bit word (seq<<32 | f32 bits), stored
// with one agent-scope atomic per element. Readers spin on their OWN element's
// seq — data arrival IS the barrier (no counter, single L3 round trip).
// Double-buffered by step parity; max WG skew is provably <2 steps, so the
// slot a WG overwrites (seq t+3) has already been consumed by every WG
// (they all read seq t+1 from it before anyone could reach step t+2).
// 0xAA workspace poison (seq=0xAAAAAAAA) never matches seq in [1,T].
// ============================================================================
template <typename TXG>
__global__ __launch_bounds__(512, 2) void lstm_rec(const TXG* __restrict__ xg,
                                                   const float* __restrict__ w_hh,
                                                   float* __restrict__ out,
                                                   unsigned long long* __restrict__ hbuf, // [2][512]
                                                   int T) {
  const int m = blockIdx.x;          // 0..15
  const int tid = threadIdx.x;       // 0..511
  const int wave = tid >> 6;
  const int lane = tid & 63;
  const int p = wave >> 1;                     // col part 0..3
  const int r = ((wave & 1) << 6) + lane;      // local row 0..127
  const int q = r >> 5;                        // gate (0=i,1=f,2=g,3=o)
  const int j = r & 31;                        // cell within slice
  const int grow = q * HD + m * 32 + j;        // global row in w_hh [0,2048)

  // Resident weights (exact fp32), 128 per thread (VGPR/AGPR-backed).
  float w[128];
  {
    const float* wp = w_hh + (size_t)grow * HD + p * 128;
#pragma unroll
    for (int i = 0; i < 32; ++i) {
      const float4 v = *reinterpret_cast<const float4*>(wp + 4 * i);
      w[4 * i + 0] = v.x; w[4 * i + 1] = v.y; w[4 * i + 2] = v.z; w[4 * i + 3] = v.w;
    }
  }

  __shared__ float h_lds[HD];
  __shared__ float red[4][128];
  __shared__ float act[128];

  float c = 0.0f;       // cell state (tid<32 owns cell m*32+tid)
  h_lds[tid] = 0.0f;    // h0 = 0
  __syncthreads();

  const int xcol = (tid >> 5) * HD + m * 32 + (tid & 31);  // gate col for tid<128
  float xgv = (tid < 128) ? xg_load1(xg + xcol) : 0.0f;

  for (int t = 0; t < T; ++t) {
    // prefetch next step's xg (latency hidden behind dot + exchange)
    float xgv_n = 0.0f;
    if (tid < 128 && t + 1 < T) xgv_n = xg_load1(xg + (size_t)(t + 1) * G4H + xcol);

    // ---- dot: 128 cols/thread, 8 independent FMA chains, wave-uniform
    //      LDS broadcast reads (conflict-free) ----
    const float4* hv4 = reinterpret_cast<const float4*>(h_lds + p * 128);
    float a0 = 0.f, a1 = 0.f, a2 = 0.f, a3 = 0.f;
    float b0 = 0.f, b1 = 0.f, b2 = 0.f, b3 = 0.f;
#pragma unroll
    for (int i = 0; i < 16; ++i) {
      const float4 h0 = hv4[2 * i];
      const float4 h1 = hv4[2 * i + 1];
      a0 = fmaf(w[8 * i + 0], h0.x, a0);
      a1 = fmaf(w[8 * i + 1], h0.y, a1);
      a2 = fmaf(w[8 * i + 2], h0.z, a2);
      a3 = fmaf(w[8 * i + 3], h0.w, a3);
      b0 = fmaf(w[8 * i + 4], h1.x, b0);
      b1 = fmaf(w[8 * i + 5], h1.y, b1);
      b2 = fmaf(w[8 * i + 6], h1.z, b2);
      b3 = fmaf(w[8 * i + 7], h1.w, b3);
    }
    red[p][r] = ((a0 + a1) + (a2 + a3)) + ((b0 + b1) + (b2 + b3));
    __syncthreads();

    // ---- gate activations (tid<128) ----
    if (tid < 128) {
      const float pre = red[0][tid] + red[1][tid] + red[2][tid] + red[3][tid] + xgv;
      act[tid] = ((tid >> 5) == 2) ? tanh_f(pre) : sigmoid_f(pre);
    }
    __syncthreads();

    // ---- cell update + broadcast (tid<32) ----
    const int slot = (t + 1) & 1;
    if (tid < 32) {
      const float i_ = act[tid], f_ = act[32 + tid], g_ = act[64 + tid], o_ = act[96 + tid];
      c = fmaf(f_, c, i_ * g_);
      const float h = o_ * tanh_f(c);
      // broadcast FIRST (critical path), out store after
      const unsigned long long pk =
          ((unsigned long long)(unsigned)(t + 1) << 32) | (unsigned long long)__float_as_uint(h);
      __hip_atomic_store(&hbuf[slot * HD + m * 32 + tid], pk,
                         __ATOMIC_RELAXED, __HIP_MEMORY_SCOPE_AGENT);
      out[(size_t)t * HD + m * 32 + tid] = h;
    }

    // ---- spin on own element: arrival = sync + data in one round trip ----
    const unsigned want = (unsigned)(t + 1);
    unsigned long long v;
    do {
      v = __hip_atomic_load(&hbuf[slot * HD + tid],
                            __ATOMIC_RELAXED, __HIP_MEMORY_SCOPE_AGENT);
    } while ((unsigned)(v >> 32) != want);
    h_lds[tid] = __uint_as_float((unsigned)v);
    __syncthreads();

    xgv = xgv_n;
  }
}

// ============================================================================
extern "C" void kernel_launch(void* const* d_in, const int* in_sizes, int n_in,
                              void* d_out, int out_size, void* d_ws, size_t ws_size,
                              hipStream_t stream) {
  const float* input = (const float*)d_in[0];
  const float* w_ih  = (const float*)d_in[1];
  const float* w_hh  = (const float*)d_in[2];
  const float* b_ih  = (const float*)d_in[3];
  float* out = (float*)d_out;
  const int T = in_sizes[0] / HD;  // 16384

  const size_t xgF32  = (size_t)T * G4H * sizeof(float);
  const size_t xgBF16 = (size_t)T * G4H * sizeof(__hip_bfloat16);
  const bool useF32 = (ws_size >= xgF32 + 16384);  // host-side, constant per session
  const size_t xgBytes = useF32 ? xgF32 : xgBF16;

  char* ws = (char*)d_ws;
  unsigned long long* hbuf =
      (unsigned long long*)(ws + ((xgBytes + 255) & ~(size_t)255));
  // No memset needed: 0xAA poison (seq=0xAAAAAAAA) never matches seq in [1,T],
  // and t=0 uses h0=0 from LDS directly (first poll waits for seq=1).

  const dim3 gA(G4H / 64, T / 64);
  if (useF32) {
    float* xg = (float*)ws;
    xg_gemm<float><<<gA, 256, 0, stream>>>(input, w_ih, b_ih, xg);
    lstm_rec<float><<<NWG, 512, 0, stream>>>(xg, w_hh, out, hbuf, T);
  } else {
    __hip_bfloat16* xg = (__hip_bfloat16*)ws;
    xg_gemm<__hip_bfloat16><<<gA, 256, 0, stream>>>(input, w_ih, b_ih, xg);
    lstm_rec<__hip_bfloat16><<<NWG, 512, 0, stream>>>(xg, w_hh, out, hbuf, T);
  }
}